// Round 8
// baseline (3475.008 us; speedup 1.0000x reference)
//
#include <hip/hip_runtime.h>
#include <hip/hip_bf16.h>

typedef short bf16x8 __attribute__((ext_vector_type(8)));
typedef float f32x4 __attribute__((ext_vector_type(4)));
typedef unsigned short u16;
typedef unsigned int u32;
typedef unsigned long long u64;

#define EPSBN 1e-3f

__device__ __forceinline__ u16 f2b(float f){
  unsigned u = __float_as_uint(f);
  return (u16)((u + 0x7fffu + ((u >> 16) & 1u)) >> 16);
}
__device__ __forceinline__ float b2f(u16 v){ return __uint_as_float(((unsigned)v) << 16); }
__device__ __forceinline__ float sigm(float x){ return 1.f/(1.f + __expf(-x)); }
__device__ __forceinline__ float tanhx(float x){ return 2.f/(1.f + __expf(-2.f*x)) - 1.f; }

union U64x2 { u64 q[2]; bf16x8 v; };

// ---------------- prep kernels ----------------

__global__ void prep_sv(const float* __restrict__ g1, const float* __restrict__ be1,
                        const float* __restrict__ m1, const float* __restrict__ v1,
                        float* __restrict__ s, float* __restrict__ tv){
  int k = blockIdx.x*256 + threadIdx.x;
  if (k < 512){
    float sv = g1[k] * rsqrtf(v1[k] + EPSBN);
    s[k] = sv;
    tv[k] = be1[k] - m1[k]*sv;
  }
}

__global__ void prep_b2p(const float* __restrict__ W2, const float* __restrict__ b2,
                         const float* __restrict__ tv, float* __restrict__ out){
  int col = blockIdx.x*256 + threadIdx.x;   // 2048
  float acc = b2[col];
  for (int k=0;k<512;++k) acc += tv[k] * W2[(size_t)k*2048 + col];
  out[col] = acc;
}

// in: [512][2048] f32 (optionally row-scaled by scale[k]) -> out bf16 [2048 perm][512]
__global__ void transpose_pack(const float* __restrict__ in, const float* __restrict__ scale,
                               u16* __restrict__ out){
  __shared__ float tile[64][65];
  int k0 = blockIdx.x * 64;
  int c0 = blockIdx.y * 64;
  int t = threadIdx.x;
  int cc = t & 63, kk0 = (t >> 6) * 16;
  #pragma unroll
  for (int i=0;i<16;++i){
    float v = in[(size_t)(k0 + kk0 + i)*2048 + c0 + cc];
    if (scale) v *= scale[k0 + kk0 + i];
    tile[kk0 + i][cc] = v;
  }
  __syncthreads();
  int cc2 = t >> 2, kp = t & 3;
  int col = c0 + cc2;
  int hcol = col & 511;
  int row = (hcol >> 5)*128 + (col >> 9)*32 + ((hcol >> 4) & 1)*16 + (col & 15);
  bf16x8 v0, v1;
  #pragma unroll
  for (int i=0;i<8;++i){
    v0[i] = (short)f2b(tile[kp*16 + i][cc2]);
    v1[i] = (short)f2b(tile[kp*16 + 8 + i][cc2]);
  }
  u16* dst = out + (size_t)row*512 + k0 + kp*16;
  *(bf16x8*)dst = v0;
  *(bf16x8*)(dst + 8) = v1;
}

// W1 [5][2048] -> [2048 perm rows][32] bf16 (K padded 5->32)
__global__ void pack_w1(const float* __restrict__ W1, u16* __restrict__ out){
  int r = blockIdx.x*256 + threadIdx.x;  // 0..2047
  int wg = r >> 7, q = (r >> 5) & 3, jt = (r >> 4) & 1, jj = r & 15;
  int col = q*512 + wg*32 + jt*16 + jj;
  #pragma unroll
  for (int k=0;k<32;++k)
    out[(size_t)r*32 + k] = (k < 5) ? f2b(W1[(size_t)k*2048 + col]) : (u16)0;
}

// x [64][512][5] f32 -> [64][512][32] bf16 zero-padded
__global__ void pack_x(const float* __restrict__ x, u16* __restrict__ out){
  int i = blockIdx.x*256 + threadIdx.x;   // exactly 64*512*32
  int k = i & 31;
  int bt = i >> 5;
  out[i] = (k < 5) ? f2b(x[(size_t)bt*5 + k]) : (u16)0;
}

__device__ __forceinline__ void pollge(const u32* p, u32 target){
  while (__hip_atomic_load(p, __ATOMIC_RELAXED, __HIP_MEMORY_SCOPE_AGENT) < target) {}
}

// ---------------- fused pipelined 3-layer LSTM scan ----------------
__global__ void __launch_bounds__(512, 2) scan_all(
    const u16* __restrict__ Ure1, const u16* __restrict__ Ure2, const u16* __restrict__ Ure3,
    const u16* __restrict__ W1p,  const u16* __restrict__ W2p,  const u16* __restrict__ W3p,
    const u16* __restrict__ xpad,
    const float* __restrict__ b1, const float* __restrict__ b2p, const float* __restrict__ b3,
    u32* __restrict__ hbuf_all, u32* __restrict__ x1seq, u32* __restrict__ xsseq,
    float* __restrict__ h3out, u32* __restrict__ cnt)
{
  const int bid = blockIdx.x;
  const int phase = bid >> 6;
  const int b6 = bid & 63;
  const int g = b6 & 3, wg = b6 >> 2;
  const int tid = threadIdx.x;
  const int w = tid >> 6, l = tid & 63;
  const int lm = l & 15, lh = (l >> 4) & 3;
  const int kp = w & 3, jt = w >> 2;
  const int bg0 = g * 16;
  const int jp = tid & 15, gb = (tid >> 4) & 15;
  const int jt2 = jp >> 3;

  const u16* Ure  = phase == 0 ? Ure1 : (phase == 1 ? Ure2 : Ure3);
  const u16* Wre  = phase == 0 ? W1p  : (phase == 1 ? W2p  : W3p);
  const float* bias = phase == 0 ? b1 : (phase == 1 ? b2p : b3);
  u32* hbuf32 = hbuf_all + (size_t)phase * 32768;
  u32* seqout = phase == 0 ? x1seq : (phase == 1 ? xsseq : nullptr);
  const u32* upseq = phase == 1 ? x1seq : (phase == 2 ? xsseq : nullptr);

  u32* cq  = cnt + (phase*4 + g)*64;
  const u32* upq = (phase > 0) ? cnt + ((phase-1)*4 + g)*64 : nullptr;

  bf16x8 aU[4][4];
  #pragma unroll
  for (int q=0;q<4;++q){
    const u16* up = Ure + (size_t)(wg*128 + q*32 + jt*16 + lm)*512 + kp*128 + lh*8;
    #pragma unroll
    for (int ks=0;ks<4;++ks){
      aU[q][ks] = *(const bf16x8*)(up + ks*32);
      asm volatile("" : "+v"(aU[q][ks]));       // pin in VGPRs: forbid remat/reload
    }
  }
  bf16x8 aW[4][4];
  bf16x8 aW1[4];
  if (phase == 0){
    if (kp == 0){
      #pragma unroll
      for (int q=0;q<4;++q){
        aW1[q] = *(const bf16x8*)(Wre + (size_t)(wg*128 + q*32 + jt*16 + lm)*32 + lh*8);
        asm volatile("" : "+v"(aW1[q]));
      }
    }
  } else {
    #pragma unroll
    for (int q=0;q<4;++q){
      const u16* wp = Wre + (size_t)(wg*128 + q*32 + jt*16 + lm)*512 + kp*128 + lh*8;
      #pragma unroll
      for (int ks=0;ks<4;++ks){
        aW[q][ks] = *(const bf16x8*)(wp + ks*32);
        asm volatile("" : "+v"(aW[q][ks]));
      }
    }
  }

  float bias0[4], bias1[4];
  if (tid < 256){
    #pragma unroll
    for (int q=0;q<4;++q){
      bias0[q] = bias[q*512 + wg*32 + 2*jp];
      bias1[q] = bias[q*512 + wg*32 + 2*jp + 1];
    }
  }

  float cs0 = 0.f, cs1 = 0.f;

  __shared__ float zex[8][4][16][18];
  const u64* hbase = (const u64*)hbuf32;

  // prologue: prefetch x[0]
  U64x2 xq[4];
  bf16x8 bx;
  u32 rv = 0;
  if (phase == 0){
    if (kp == 0)
      bx = *(const bf16x8*)(xpad + ((size_t)(bg0+lm)*512 + 0)*32 + lh*8);
  } else {
    pollge(upq, 64u);
    const u64* xp = (const u64*)upseq + ((size_t)(bg0+lm)*512 + 0)*128 + kp*32 + lh*2;
    #pragma unroll
    for (int ks=0;ks<4;++ks){
      xq[ks].q[0] = __hip_atomic_load(xp + ks*8,     __ATOMIC_RELAXED, __HIP_MEMORY_SCOPE_AGENT);
      xq[ks].q[1] = __hip_atomic_load(xp + ks*8 + 1, __ATOMIC_RELAXED, __HIP_MEMORY_SCOPE_AGENT);
    }
    if (phase == 1 && tid < 256)
      rv = __hip_atomic_load(upseq + ((size_t)(bg0+gb)*512 + 0)*256 + wg*16 + jp,
                             __ATOMIC_RELAXED, __HIP_MEMORY_SCOPE_AGENT);
  }

  for (int t=0; t<512; ++t){
    f32x4 acc[4] = {};
    const u32 rvc = rv;

    // input projection from prefetched registers
    if (phase == 0){
      if (kp == 0){
        #pragma unroll
        for (int q=0;q<4;++q)
          acc[q] = __builtin_amdgcn_mfma_f32_16x16x32_bf16(aW1[q], bx, acc[q], 0,0,0);
      }
    } else {
      #pragma unroll
      for (int ks=0;ks<4;++ks){
        #pragma unroll
        for (int q=0;q<4;++q)
          acc[q] = __builtin_amdgcn_mfma_f32_16x16x32_bf16(aW[q][ks], xq[ks].v, acc[q], 0,0,0);
      }
    }

    // wait for h_{t-1}; issue h loads ASAP
    pollge(cq, 64u*(u32)t);
    U64x2 hq[4];
    {
      const u64* hp = hbase + (size_t)(((t+1)&1)*64 + bg0 + lm)*128 + kp*32 + lh*2;
      #pragma unroll
      for (int ks=0;ks<4;++ks){
        hq[ks].q[0] = __hip_atomic_load(hp + ks*8,     __ATOMIC_RELAXED, __HIP_MEMORY_SCOPE_AGENT);
        hq[ks].q[1] = __hip_atomic_load(hp + ks*8 + 1, __ATOMIC_RELAXED, __HIP_MEMORY_SCOPE_AGENT);
      }
    }

    // prefetch x[t+1] (hidden under h-RT + step tail)
    if (t < 511){
      if (phase == 0){
        if (kp == 0)
          bx = *(const bf16x8*)(xpad + ((size_t)(bg0+lm)*512 + (t+1))*32 + lh*8);
      } else {
        pollge(upq, 64u*(u32)(t+2));
        const u64* xp = (const u64*)upseq + ((size_t)(bg0+lm)*512 + (t+1))*128 + kp*32 + lh*2;
        #pragma unroll
        for (int ks=0;ks<4;++ks){
          xq[ks].q[0] = __hip_atomic_load(xp + ks*8,     __ATOMIC_RELAXED, __HIP_MEMORY_SCOPE_AGENT);
          xq[ks].q[1] = __hip_atomic_load(xp + ks*8 + 1, __ATOMIC_RELAXED, __HIP_MEMORY_SCOPE_AGENT);
        }
        if (phase == 1 && tid < 256)
          rv = __hip_atomic_load(upseq + ((size_t)(bg0+gb)*512 + (t+1))*256 + wg*16 + jp,
                                 __ATOMIC_RELAXED, __HIP_MEMORY_SCOPE_AGENT);
      }
    }

    // recurrent h @ U
    #pragma unroll
    for (int ks=0;ks<4;++ks){
      #pragma unroll
      for (int q=0;q<4;++q)
        acc[q] = __builtin_amdgcn_mfma_f32_16x16x32_bf16(aU[q][ks], hq[ks].v, acc[q], 0,0,0);
    }

    // K-partial reduce via LDS
    #pragma unroll
    for (int q=0;q<4;++q){
      #pragma unroll
      for (int r=0;r<4;++r)
        zex[q*2+jt][kp][lh*4 + r][lm] = acc[q][r];
    }
    __syncthreads();                            // barrier (1)

    // gates + direct-register publish (tid<256)
    if (tid < 256){
      const int r0 = (2*jp) & 15, r1 = r0 + 1;
      float zv0[4], zv1[4];
      #pragma unroll
      for (int q=0;q<4;++q){
        const int ti = q*2 + jt2;
        zv0[q] = zex[ti][0][r0][gb] + zex[ti][1][r0][gb]
               + zex[ti][2][r0][gb] + zex[ti][3][r0][gb] + bias0[q];
        zv1[q] = zex[ti][0][r1][gb] + zex[ti][1][r1][gb]
               + zex[ti][2][r1][gb] + zex[ti][3][r1][gb] + bias1[q];
      }
      float iv = sigm(zv0[0]), fv = sigm(zv0[1]), gv = tanhx(zv0[2]), ov = sigm(zv0[3]);
      cs0 = fv * cs0 + iv * gv;
      float hv0 = ov * tanhx(cs0);
      iv = sigm(zv1[0]); fv = sigm(zv1[1]); gv = tanhx(zv1[2]); ov = sigm(zv1[3]);
      cs1 = fv * cs1 + iv * gv;
      float hv1 = ov * tanhx(cs1);

      const u32 pw = (u32)f2b(hv0) | ((u32)f2b(hv1) << 16);
      __hip_atomic_store(hbuf32 + (size_t)((t&1)*64 + bg0 + gb)*256 + wg*16 + jp, pw,
                         __ATOMIC_RELAXED, __HIP_MEMORY_SCOPE_AGENT);
      if (phase == 0){
        __hip_atomic_store(seqout + ((size_t)(bg0+gb)*512 + t)*256 + wg*16 + jp, pw,
                           __ATOMIC_RELAXED, __HIP_MEMORY_SCOPE_AGENT);
      } else if (phase == 1){
        float x1r0 = b2f((u16)(rvc & 0xffffu));
        float x1r1 = b2f((u16)(rvc >> 16));
        u32 sv = (u32)f2b(x1r0 + hv0) | ((u32)f2b(x1r1 + hv1) << 16);
        __hip_atomic_store(seqout + ((size_t)(bg0+gb)*512 + t)*256 + wg*16 + jp, sv,
                           __ATOMIC_RELAXED, __HIP_MEMORY_SCOPE_AGENT);
      } else if (t == 511){
        h3out[(size_t)(bg0+gb)*512 + wg*32 + 2*jp]     = hv0;
        h3out[(size_t)(bg0+gb)*512 + wg*32 + 2*jp + 1] = hv1;
      }
      asm volatile("s_waitcnt vmcnt(0)" ::: "memory");
      if ((tid & 63) == 0)
        __hip_atomic_fetch_add(cq, 1u, __ATOMIC_RELAXED, __HIP_MEMORY_SCOPE_AGENT);
    }
    __syncthreads();                            // barrier (2): zex WAR for next step
  }
}

// ---------------- dense heads ----------------
__global__ void __launch_bounds__(256) head_k(
    const float* __restrict__ h3,
    const float* __restrict__ d1w, const float* __restrict__ d1b,
    const float* __restrict__ g2, const float* __restrict__ be2,
    const float* __restrict__ m2, const float* __restrict__ v2,
    const float* __restrict__ d2w, const float* __restrict__ d2b,
    const float* __restrict__ hw, const float* __restrict__ hb,
    const float* __restrict__ d4w, const float* __restrict__ d4b,
    const float* __restrict__ d5w, const float* __restrict__ d5b,
    const float* __restrict__ rw, const float* __restrict__ rb,
    float* __restrict__ out)
{
  __shared__ float hl[512];
  __shared__ float a1[32], a2[16], c1[128], c2[64];
  int b = blockIdx.x, t = threadIdx.x;
  for (int i=t; i<512; i+=256) hl[i] = h3[(size_t)b*512 + i];
  __syncthreads();
  if (t < 32){
    float acc = d1b[t];
    for (int k=0;k<512;++k) acc += hl[k] * d1w[(size_t)k*32 + t];
    a1[t] = (acc - m2[t]) * (g2[t] * rsqrtf(v2[t] + EPSBN)) + be2[t];
  } else if (t >= 128){
    int i = t - 128;
    float acc = d4b[i];
    for (int k=0;k<512;++k) acc += hl[k] * d4w[(size_t)k*128 + i];
    c1[i] = acc;
  }
  __syncthreads();
  if (t < 16){
    float acc = d2b[t];
    for (int k=0;k<32;++k) acc += a1[k] * d2w[k*16 + t];
    a2[t] = acc;
  } else if (t >= 64 && t < 128){
    int i = t - 64;
    float acc = d5b[i];
    for (int k=0;k<128;++k) acc += c1[k] * d5w[k*64 + i];
    c2[i] = acc;
  }
  __syncthreads();
  if (t == 0){
    float acc = hb[0];
    for (int k=0;k<16;++k) acc += a2[k] * hw[k];
    out[b] = 1.f/(1.f + __expf(-acc));
  } else if (t >= 32 && t < 37){
    int i = t - 32;
    float acc = rb[i];
    for (int k=0;k<64;++k) acc += c2[k] * rw[k*5 + i];
    out[64 + b*5 + i] = acc;
  }
}

// ---------------- launch ----------------
extern "C" void kernel_launch(void* const* d_in, const int* in_sizes, int n_in,
                              void* d_out, int out_size, void* d_ws, size_t ws_size,
                              hipStream_t stream)
{
  const float* x   = (const float*)d_in[0];
  const float* W1  = (const float*)d_in[1];
  const float* U1  = (const float*)d_in[2];
  const float* b1  = (const float*)d_in[3];
  const float* g1  = (const float*)d_in[4];
  const float* be1 = (const float*)d_in[5];
  const float* m1  = (const float*)d_in[6];
  const float* v1  = (const float*)d_in[7];
  const float* W2  = (const float*)d_in[8];
  const float* U2  = (const float*)d_in[9];
  const float* b2  = (const float*)d_in[10];
  const float* W3  = (const float*)d_in[11];
  const float* U3  = (const float*)d_in[12];
  const float* b3  = (const float*)d_in[13];
  const float* d1w = (const float*)d_in[14];
  const float* d1b = (const float*)d_in[15];
  const float* g2  = (const float*)d_in[16];
  const float* be2 = (const float*)d_in[17];
  const float* m2  = (const float*)d_in[18];
  const float* v2  = (const float*)d_in[19];
  const float* d2w = (const float*)d_in[20];
  const float* d2b = (const float*)d_in[21];
  const float* hw  = (const float*)d_in[22];
  const float* hb  = (const float*)d_in[23];
  const float* d4w = (const float*)d_in[24];
  const float* d4b = (const float*)d_in[25];
  const float* d5w = (const float*)d_in[26];
  const float* d5b = (const float*)d_in[27];
  const float* rw  = (const float*)d_in[28];
  const float* rb  = (const float*)d_in[29];

  char* ws = (char*)d_ws;
  constexpr size_t SZ_W   = 2048ull*512*2;
  constexpr size_t o_Ure1 = 0;
  constexpr size_t o_Ure2 = o_Ure1 + SZ_W;
  constexpr size_t o_Ure3 = o_Ure2 + SZ_W;
  constexpr size_t o_W2p  = o_Ure3 + SZ_W;
  constexpr size_t o_W3p  = o_W2p + SZ_W;
  constexpr size_t o_W1p  = o_W3p + SZ_W;
  constexpr size_t o_xpad = o_W1p + 2048ull*32*2;
  constexpr size_t o_b2p  = o_xpad + 64ull*512*32*2;
  constexpr size_t o_s    = o_b2p + 2048ull*4;
  constexpr size_t o_tv   = o_s + 512ull*4;
  constexpr size_t o_h3   = o_tv + 512ull*4;
  constexpr size_t o_h    = o_h3 + 64ull*512*4;
  constexpr size_t SZ_HP  = 2ull*64*256*4;
  constexpr size_t SZ_H   = 3*SZ_HP;
  constexpr size_t o_cnt  = o_h + SZ_H;
  constexpr size_t o_x1   = o_cnt + 4096;
  constexpr size_t o_xs   = o_x1 + 64ull*512*512*2;

  u16* Ure1 = (u16*)(ws + o_Ure1);
  u16* Ure2 = (u16*)(ws + o_Ure2);
  u16* Ure3 = (u16*)(ws + o_Ure3);
  u16* W2p  = (u16*)(ws + o_W2p);
  u16* W3p  = (u16*)(ws + o_W3p);
  u16* W1p  = (u16*)(ws + o_W1p);
  u16* xpad = (u16*)(ws + o_xpad);
  u32* x1p  = (u32*)(ws + o_x1);
  u32* xsp  = (u32*)(ws + o_xs);

  hipMemsetAsync(ws + o_h, 0, SZ_H + 4096, stream);

  prep_sv<<<dim3(2), dim3(256), 0, stream>>>(g1, be1, m1, v1, (float*)(ws+o_s), (float*)(ws+o_tv));
  transpose_pack<<<dim3(8,32), dim3(256), 0, stream>>>(U1, nullptr, Ure1);
  transpose_pack<<<dim3(8,32), dim3(256), 0, stream>>>(U2, nullptr, Ure2);
  transpose_pack<<<dim3(8,32), dim3(256), 0, stream>>>(U3, nullptr, Ure3);
  transpose_pack<<<dim3(8,32), dim3(256), 0, stream>>>(W3, nullptr, W3p);
  transpose_pack<<<dim3(8,32), dim3(256), 0, stream>>>(W2, (const float*)(ws+o_s), W2p);
  prep_b2p<<<dim3(8), dim3(256), 0, stream>>>(W2, b2, (const float*)(ws+o_tv), (float*)(ws+o_b2p));
  pack_w1<<<dim3(8), dim3(256), 0, stream>>>(W1, W1p);
  pack_x<<<dim3(4096), dim3(256), 0, stream>>>(x, xpad);

  scan_all<<<dim3(192), dim3(512), 0, stream>>>(
      Ure1, Ure2, Ure3, W1p, W2p, W3p, xpad,
      b1, (const float*)(ws+o_b2p), b3,
      (u32*)(ws+o_h), x1p, xsp,
      (float*)(ws+o_h3), (u32*)(ws+o_cnt));

  head_k<<<dim3(64), dim3(256), 0, stream>>>((const float*)(ws+o_h3),
      d1w, d1b, g2, be2, m2, v2, d2w, d2b, hw, hb, d4w, d4b, d5w, d5b, rw, rb,
      (float*)d_out);
}

// Round 10
// 2339.792 us; speedup vs baseline: 1.4852x; 1.4852x over previous
//
#include <hip/hip_runtime.h>
#include <hip/hip_bf16.h>

typedef short bf16x8 __attribute__((ext_vector_type(8)));
typedef float f32x4 __attribute__((ext_vector_type(4)));
typedef unsigned short u16;
typedef unsigned int u32;
typedef unsigned long long u64;

#define EPSBN 1e-3f

__device__ __forceinline__ u16 f2b(float f){
  unsigned u = __float_as_uint(f);
  return (u16)((u + 0x7fffu + ((u >> 16) & 1u)) >> 16);
}
__device__ __forceinline__ float b2f(u16 v){ return __uint_as_float(((unsigned)v) << 16); }
__device__ __forceinline__ float sigm(float x){ return 1.f/(1.f + __expf(-x)); }
__device__ __forceinline__ float tanhx(float x){ return 2.f/(1.f + __expf(-2.f*x)) - 1.f; }

union U64x2 { u64 q[2]; bf16x8 v; };
union BP    { u32 p[4]; bf16x8 v; };

// ---------------- prep kernels ----------------

__global__ void prep_sv(const float* __restrict__ g1, const float* __restrict__ be1,
                        const float* __restrict__ m1, const float* __restrict__ v1,
                        float* __restrict__ s, float* __restrict__ tv){
  int k = blockIdx.x*256 + threadIdx.x;
  if (k < 512){
    float sv = g1[k] * rsqrtf(v1[k] + EPSBN);
    s[k] = sv;
    tv[k] = be1[k] - m1[k]*sv;
  }
}

__global__ void prep_b2p(const float* __restrict__ W2, const float* __restrict__ b2,
                         const float* __restrict__ tv, float* __restrict__ out){
  int col = blockIdx.x*256 + threadIdx.x;   // 2048
  float acc = b2[col];
  for (int k=0;k<512;++k) acc += tv[k] * W2[(size_t)k*2048 + col];
  out[col] = acc;
}

// in: [512][2048] f32 (optionally row-scaled) -> bf16 [2048 perm][512]
__global__ void transpose_pack(const float* __restrict__ in, const float* __restrict__ scale,
                               u16* __restrict__ out){
  __shared__ float tile[64][65];
  int k0 = blockIdx.x * 64;
  int c0 = blockIdx.y * 64;
  int t = threadIdx.x;
  int cc = t & 63, kk0 = (t >> 6) * 16;
  #pragma unroll
  for (int i=0;i<16;++i){
    float v = in[(size_t)(k0 + kk0 + i)*2048 + c0 + cc];
    if (scale) v *= scale[k0 + kk0 + i];
    tile[kk0 + i][cc] = v;
  }
  __syncthreads();
  int cc2 = t >> 2, kp = t & 3;
  int col = c0 + cc2;
  int hcol = col & 511;
  int row = (hcol >> 5)*128 + (col >> 9)*32 + ((hcol >> 4) & 1)*16 + (col & 15);
  bf16x8 v0, v1;
  #pragma unroll
  for (int i=0;i<8;++i){
    v0[i] = (short)f2b(tile[kp*16 + i][cc2]);
    v1[i] = (short)f2b(tile[kp*16 + 8 + i][cc2]);
  }
  u16* dst = out + (size_t)row*512 + k0 + kp*16;
  *(bf16x8*)dst = v0;
  *(bf16x8*)(dst + 8) = v1;
}

__global__ void pack_w1(const float* __restrict__ W1, u16* __restrict__ out){
  int r = blockIdx.x*256 + threadIdx.x;  // 0..2047
  int wg = r >> 7, q = (r >> 5) & 3, jt = (r >> 4) & 1, jj = r & 15;
  int col = q*512 + wg*32 + jt*16 + jj;
  #pragma unroll
  for (int k=0;k<32;++k)
    out[(size_t)r*32 + k] = (k < 5) ? f2b(W1[(size_t)k*2048 + col]) : (u16)0;
}

__global__ void pack_x(const float* __restrict__ x, u16* __restrict__ out){
  int i = blockIdx.x*256 + threadIdx.x;   // 64*512*32
  int k = i & 31;
  int bt = i >> 5;
  out[i] = (k < 5) ? f2b(x[(size_t)bt*5 + k]) : (u16)0;
}

__device__ __forceinline__ void pollge(const u32* p, u32 target){
  while (__hip_atomic_load(p, __ATOMIC_RELAXED, __HIP_MEMORY_SCOPE_AGENT) < target) {}
}

// ---------------- fused pipelined 3-layer LSTM scan ----------------
// 192 blocks = 3 phases x (4 groups x 16 WGs), 256 thr (4 waves, round-4 shape).
// h-path: tagged u64 publish (fire-and-forget) + reader retry  -> ~1 fabric RT.
// seq-path: counter with LAZY bump — at step t, each wave's h-retry vmcnt wait
// has (in-order) drained its step-(t-1) seq stores, so tid0 bumps for t-1 after
// barrier(1) with no explicit drain; tail flush confirms step 511.
// Barriers are raw s_barrier (no compiler vmcnt(0) drain): barrier1 carries
// lgkmcnt(0) for zex-write visibility; barrier2 WAR safety holds because
// arrival implies LDS reads completed (gate values consumed before publish).
__global__ void __launch_bounds__(256, 1) scan_all(
    const u16* __restrict__ Ure1, const u16* __restrict__ Ure2, const u16* __restrict__ Ure3,
    const u16* __restrict__ W1p,  const u16* __restrict__ W2p,  const u16* __restrict__ W3p,
    const u16* __restrict__ xpad,
    const float* __restrict__ b1, const float* __restrict__ b2p, const float* __restrict__ b3,
    u32* __restrict__ hbuf_all,   // 3 x [2][64][512] tagged u32
    u32* __restrict__ x1seq,      // [64][512][256] u32 packed pairs
    u32* __restrict__ xsseq,      // [64][512][256] u32
    float* __restrict__ h3out, u32* __restrict__ cnt)
{
  const int bid = blockIdx.x;
  const int phase = bid >> 6;
  const int b6 = bid & 63;
  const int g = b6 & 3, wg = b6 >> 2;
  const int tid = threadIdx.x;
  const int w = tid >> 6, l = tid & 63;
  const int lm = l & 15, lh = l >> 4;
  const int bg0 = g * 16;
  const int jp = tid & 15, gb = tid >> 4;   // gate thread: batch gb, cols 2jp,2jp+1
  const int ti0 = jp >> 3;

  const u16* Ure  = phase == 0 ? Ure1 : (phase == 1 ? Ure2 : Ure3);
  const u16* Wre  = phase == 0 ? W1p  : (phase == 1 ? W2p  : W3p);
  const float* bias = phase == 0 ? b1 : (phase == 1 ? b2p : b3);
  u32* hbuf32 = hbuf_all + (size_t)phase * 65536;           // [2][64][512]
  u32* seqout = phase == 0 ? x1seq : (phase == 1 ? xsseq : nullptr);
  const u32* upseq = phase == 1 ? x1seq : (phase == 2 ? xsseq : nullptr);

  u32* cq  = cnt + (phase*4 + g)*64;                        // own seq-confirm counter
  const u32* upq = (phase > 0) ? cnt + ((phase-1)*4 + g)*64 : nullptr;

  // resident A-frags (round-4 layout): 8 tiles (gate q, half jt), 4 K-frags
  bf16x8 aU[8][4];
  #pragma unroll
  for (int q=0;q<4;++q)
    #pragma unroll
    for (int jt=0;jt<2;++jt){
      const u16* up = Ure + (size_t)(wg*128 + q*32 + jt*16 + lm)*512 + w*128 + lh*8;
      #pragma unroll
      for (int ks=0;ks<4;++ks) aU[q*2+jt][ks] = *(const bf16x8*)(up + ks*32);
    }
  bf16x8 aW[8][4];
  bf16x8 aW1[8];
  if (phase == 0){
    if (w == 0){
      #pragma unroll
      for (int q=0;q<4;++q)
        #pragma unroll
        for (int jt=0;jt<2;++jt)
          aW1[q*2+jt] = *(const bf16x8*)(Wre + (size_t)(wg*128 + q*32 + jt*16 + lm)*32 + lh*8);
    }
  } else {
    #pragma unroll
    for (int q=0;q<4;++q)
      #pragma unroll
      for (int jt=0;jt<2;++jt){
        const u16* wp = Wre + (size_t)(wg*128 + q*32 + jt*16 + lm)*512 + w*128 + lh*8;
        #pragma unroll
        for (int ks=0;ks<4;++ks) aW[q*2+jt][ks] = *(const bf16x8*)(wp + ks*32);
      }
  }

  float bias0[4], bias1[4];
  #pragma unroll
  for (int q=0;q<4;++q){
    bias0[q] = bias[q*512 + wg*32 + 2*jp];
    bias1[q] = bias[q*512 + wg*32 + 2*jp + 1];
  }

  float cs0 = 0.f, cs1 = 0.f;

  __shared__ float zex[8][4][16][18];          // [tile][K-part][j=m][b=n]
  const u64 tagmask = 0x0000FFFF0000FFFFull;

  // ---- prologue: prefetch x[0] (+ residual) ----
  U64x2 xq[4];
  bf16x8 bx;
  u32 rv = 0;
  if (phase == 0){
    if (w == 0)
      bx = *(const bf16x8*)(xpad + ((size_t)(bg0+lm)*512 + 0)*32 + lh*8);
  } else {
    pollge(upq, 16u);                        // x[0] confirmed
    const u64* xp = (const u64*)upseq + ((size_t)(bg0+lm)*512 + 0)*128 + w*32 + lh*2;
    #pragma unroll
    for (int ks=0;ks<4;++ks){
      xq[ks].q[0] = __hip_atomic_load(xp + ks*8,     __ATOMIC_RELAXED, __HIP_MEMORY_SCOPE_AGENT);
      xq[ks].q[1] = __hip_atomic_load(xp + ks*8 + 1, __ATOMIC_RELAXED, __HIP_MEMORY_SCOPE_AGENT);
    }
    if (phase == 1)
      rv = __hip_atomic_load(upseq + ((size_t)(bg0+gb)*512 + 0)*256 + wg*16 + jp,
                             __ATOMIC_RELAXED, __HIP_MEMORY_SCOPE_AGENT);
  }

  for (int t=0; t<512; ++t){
    f32x4 acc[8] = {};
    const u32 rvc = rv;

    // early upq sample for x[t+1] gate (wait hidden under x-MFMA + h-retry)
    u32 upv = 0xffffffffu;
    if (phase > 0 && t < 511)
      upv = __hip_atomic_load(upq, __ATOMIC_RELAXED, __HIP_MEMORY_SCOPE_AGENT);

    // -------- input projection from prefetched regs --------
    if (phase == 0){
      if (w == 0){
        #pragma unroll
        for (int i=0;i<8;++i)
          acc[i] = __builtin_amdgcn_mfma_f32_16x16x32_bf16(aW1[i], bx, acc[i], 0,0,0);
      }
    } else {
      #pragma unroll
      for (int ks=0;ks<4;++ks){
        #pragma unroll
        for (int i=0;i<8;++i)
          acc[i] = __builtin_amdgcn_mfma_f32_16x16x32_bf16(aW[i][ks], xq[ks].v, acc[i], 0,0,0);
      }
    }

    // -------- recurrent h @ U via tagged retry (skip t=0: h_{-1}=0) --------
    if (t > 0){
      const int slot = (t+1) & 1;
      const u64* hp = (const u64*)hbuf32
                    + (size_t)(slot*64 + bg0 + lm)*256 + w*64 + lh*4;
      const u32 tg = (u32)t;
      const u64 want = (u64)tg | ((u64)tg << 32);
      u64 raw[16];
      bool ok;
      do {
        #pragma unroll
        for (int ks=0;ks<4;++ks)
          #pragma unroll
          for (int qq=0;qq<4;++qq)
            raw[ks*4+qq] = __hip_atomic_load(hp + ks*16 + qq,
                                             __ATOMIC_RELAXED, __HIP_MEMORY_SCOPE_AGENT);
        u64 bad = 0;
        #pragma unroll
        for (int i=0;i<16;++i) bad |= (raw[i] & tagmask) ^ want;
        ok = __all(bad == 0);
      } while (!ok);
      #pragma unroll
      for (int ks=0;ks<4;++ks){
        BP bp;
        #pragma unroll
        for (int qq=0;qq<4;++qq){
          u32 lo = (u32)raw[ks*4+qq];
          u32 hi = (u32)(raw[ks*4+qq] >> 32);
          bp.p[qq] = (lo >> 16) | (hi & 0xFFFF0000u);
        }
        #pragma unroll
        for (int i=0;i<8;++i)
          acc[i] = __builtin_amdgcn_mfma_f32_16x16x32_bf16(aU[i][ks], bp.v, acc[i], 0,0,0);
      }
    }

    // -------- prefetch x[t+1] (+residual); gate on early-sampled counter --------
    if (t < 511){
      if (phase == 0){
        if (w == 0)
          bx = *(const bf16x8*)(xpad + ((size_t)(bg0+lm)*512 + (t+1))*32 + lh*8);
      } else {
        const u32 tgt = 16u*(u32)(t+2);
        if (upv < tgt) pollge(upq, tgt);
        const u64* xp = (const u64*)upseq + ((size_t)(bg0+lm)*512 + (t+1))*128 + w*32 + lh*2;
        #pragma unroll
        for (int ks=0;ks<4;++ks){
          xq[ks].q[0] = __hip_atomic_load(xp + ks*8,     __ATOMIC_RELAXED, __HIP_MEMORY_SCOPE_AGENT);
          xq[ks].q[1] = __hip_atomic_load(xp + ks*8 + 1, __ATOMIC_RELAXED, __HIP_MEMORY_SCOPE_AGENT);
        }
        if (phase == 1)
          rv = __hip_atomic_load(upseq + ((size_t)(bg0+gb)*512 + (t+1))*256 + wg*16 + jp,
                                 __ATOMIC_RELAXED, __HIP_MEMORY_SCOPE_AGENT);
      }
    }

    // -------- K-partial reduce --------
    #pragma unroll
    for (int i=0;i<8;++i){
      #pragma unroll
      for (int r=0;r<4;++r)
        zex[i][w][lh*4 + r][lm] = acc[i][r];   // [j=m][b=n]
    }
    asm volatile("s_waitcnt lgkmcnt(0)\n\ts_barrier" ::: "memory");   // barrier(1)

    // lazy seq-confirm: all waves passed h-retry waits => step t-1 seq stores drained
    if (tid == 0 && phase < 2 && t > 0)
      __hip_atomic_fetch_add(cq, 1u, __ATOMIC_RELAXED, __HIP_MEMORY_SCOPE_AGENT);

    // -------- gates + direct-register tagged publish --------
    {
      const int r0 = (2*jp) & 15, r1 = r0 + 1;
      float zv0[4], zv1[4];
      #pragma unroll
      for (int q=0;q<4;++q){
        const int ti = q*2 + ti0;
        zv0[q] = zex[ti][0][r0][gb] + zex[ti][1][r0][gb]
               + zex[ti][2][r0][gb] + zex[ti][3][r0][gb] + bias0[q];
        zv1[q] = zex[ti][0][r1][gb] + zex[ti][1][r1][gb]
               + zex[ti][2][r1][gb] + zex[ti][3][r1][gb] + bias1[q];
      }
      float iv = sigm(zv0[0]), fv = sigm(zv0[1]), gv = tanhx(zv0[2]), ov = sigm(zv0[3]);
      cs0 = fv * cs0 + iv * gv;
      float hv0 = ov * tanhx(cs0);
      iv = sigm(zv1[0]); fv = sigm(zv1[1]); gv = tanhx(zv1[2]); ov = sigm(zv1[3]);
      cs1 = fv * cs1 + iv * gv;
      float hv1 = ov * tanhx(cs1);

      // tagged h publish: fire-and-forget u64
      const u32 tagv = (u32)(t + 1);
      u32 w0 = ((u32)f2b(hv0) << 16) | tagv;
      u32 w1 = ((u32)f2b(hv1) << 16) | tagv;
      __hip_atomic_store((u64*)(hbuf32 + (size_t)((t&1)*64 + bg0 + gb)*512 + wg*32) + jp,
                         (u64)w0 | ((u64)w1 << 32),
                         __ATOMIC_RELAXED, __HIP_MEMORY_SCOPE_AGENT);

      if (phase == 0){
        u32 sv = (u32)f2b(hv0) | ((u32)f2b(hv1) << 16);
        __hip_atomic_store(seqout + ((size_t)(bg0+gb)*512 + t)*256 + wg*16 + jp, sv,
                           __ATOMIC_RELAXED, __HIP_MEMORY_SCOPE_AGENT);
      } else if (phase == 1){
        float x1r0 = b2f((u16)(rvc & 0xffffu));
        float x1r1 = b2f((u16)(rvc >> 16));
        u32 sv = (u32)f2b(x1r0 + hv0) | ((u32)f2b(x1r1 + hv1) << 16);
        __hip_atomic_store(seqout + ((size_t)(bg0+gb)*512 + t)*256 + wg*16 + jp, sv,
                           __ATOMIC_RELAXED, __HIP_MEMORY_SCOPE_AGENT);
      } else if (t == 511){
        h3out[(size_t)(bg0+gb)*512 + wg*32 + 2*jp]     = hv0;
        h3out[(size_t)(bg0+gb)*512 + wg*32 + 2*jp + 1] = hv1;
      }
    }
    asm volatile("s_barrier" ::: "memory");    // barrier(2): zex WAR (reads consumed)
  }

  // ---- tail: flush last seq confirmation (step 511) ----
  if (phase < 2){
    asm volatile("s_waitcnt vmcnt(0)" ::: "memory");
    __syncthreads();
    if (tid == 0)
      __hip_atomic_fetch_add(cq, 1u, __ATOMIC_RELAXED, __HIP_MEMORY_SCOPE_AGENT);
  }
}

// ---------------- dense heads ----------------
__global__ void __launch_bounds__(256) head_k(
    const float* __restrict__ h3,
    const float* __restrict__ d1w, const float* __restrict__ d1b,
    const float* __restrict__ g2, const float* __restrict__ be2,
    const float* __restrict__ m2, const float* __restrict__ v2,
    const float* __restrict__ d2w, const float* __restrict__ d2b,
    const float* __restrict__ hw, const float* __restrict__ hb,
    const float* __restrict__ d4w, const float* __restrict__ d4b,
    const float* __restrict__ d5w, const float* __restrict__ d5b,
    const float* __restrict__ rw, const float* __restrict__ rb,
    float* __restrict__ out)
{
  __shared__ float hl[512];
  __shared__ float a1[32], a2[16], c1[128], c2[64];
  int b = blockIdx.x, t = threadIdx.x;
  for (int i=t; i<512; i+=256) hl[i] = h3[(size_t)b*512 + i];
  __syncthreads();
  if (t < 32){
    float acc = d1b[t];
    for (int k=0;k<512;++k) acc += hl[k] * d1w[(size_t)k*32 + t];
    a1[t] = (acc - m2[t]) * (g2[t] * rsqrtf(v2[t] + EPSBN)) + be2[t];
  } else if (t >= 128){
    int i = t - 128;
    float acc = d4b[i];
    for (int k=0;k<512;++k) acc += hl[k] * d4w[(size_t)k*128 + i];
    c1[i] = acc;
  }
  __syncthreads();
  if (t < 16){
    float acc = d2b[t];
    for (int k=0;k<32;++k) acc += a1[k] * d2w[k*16 + t];
    a2[t] = acc;
  } else if (t >= 64 && t < 128){
    int i = t - 64;
    float acc = d5b[i];
    for (int k=0;k<128;++k) acc += c1[k] * d5w[k*64 + i];
    c2[i] = acc;
  }
  __syncthreads();
  if (t == 0){
    float acc = hb[0];
    for (int k=0;k<16;++k) acc += a2[k] * hw[k];
    out[b] = 1.f/(1.f + __expf(-acc));
  } else if (t >= 32 && t < 37){
    int i = t - 32;
    float acc = rb[i];
    for (int k=0;k<64;++k) acc += c2[k] * rw[k*5 + i];
    out[64 + b*5 + i] = acc;
  }
}

// ---------------- launch ----------------
extern "C" void kernel_launch(void* const* d_in, const int* in_sizes, int n_in,
                              void* d_out, int out_size, void* d_ws, size_t ws_size,
                              hipStream_t stream)
{
  const float* x   = (const float*)d_in[0];
  const float* W1  = (const float*)d_in[1];
  const float* U1  = (const float*)d_in[2];
  const float* b1  = (const float*)d_in[3];
  const float* g1  = (const float*)d_in[4];
  const float* be1 = (const float*)d_in[5];
  const float* m1  = (const float*)d_in[6];
  const float* v1  = (const float*)d_in[7];
  const float* W2  = (const float*)d_in[8];
  const float* U2  = (const float*)d_in[9];
  const float* b2  = (const float*)d_in[10];
  const float* W3  = (const float*)d_in[11];
  const float* U3  = (const float*)d_in[12];
  const float* b3  = (const float*)d_in[13];
  const float* d1w = (const float*)d_in[14];
  const float* d1b = (const float*)d_in[15];
  const float* g2  = (const float*)d_in[16];
  const float* be2 = (const float*)d_in[17];
  const float* m2  = (const float*)d_in[18];
  const float* v2  = (const float*)d_in[19];
  const float* d2w = (const float*)d_in[20];
  const float* d2b = (const float*)d_in[21];
  const float* hw  = (const float*)d_in[22];
  const float* hb  = (const float*)d_in[23];
  const float* d4w = (const float*)d_in[24];
  const float* d4b = (const float*)d_in[25];
  const float* d5w = (const float*)d_in[26];
  const float* d5b = (const float*)d_in[27];
  const float* rw  = (const float*)d_in[28];
  const float* rb  = (const float*)d_in[29];

  char* ws = (char*)d_ws;
  constexpr size_t SZ_W   = 2048ull*512*2;
  constexpr size_t o_Ure1 = 0;
  constexpr size_t o_Ure2 = o_Ure1 + SZ_W;
  constexpr size_t o_Ure3 = o_Ure2 + SZ_W;
  constexpr size_t o_W2p  = o_Ure3 + SZ_W;
  constexpr size_t o_W3p  = o_W2p + SZ_W;
  constexpr size_t o_W1p  = o_W3p + SZ_W;
  constexpr size_t o_xpad = o_W1p + 2048ull*32*2;
  constexpr size_t o_b2p  = o_xpad + 64ull*512*32*2;
  constexpr size_t o_s    = o_b2p + 2048ull*4;
  constexpr size_t o_tv   = o_s + 512ull*4;
  constexpr size_t o_h3   = o_tv + 512ull*4;
  constexpr size_t o_h    = o_h3 + 64ull*512*4;    // 3 x [2][64][512] tagged u32
  constexpr size_t SZ_HP  = 2ull*64*512*4;         // 262144 per phase
  constexpr size_t SZ_H   = 3*SZ_HP;
  constexpr size_t o_cnt  = o_h + SZ_H;            // 3 x 4 x 64 u32
  constexpr size_t o_x1   = o_cnt + 4096;
  constexpr size_t o_xs   = o_x1 + 64ull*512*512*2;

  u16* Ure1 = (u16*)(ws + o_Ure1);
  u16* Ure2 = (u16*)(ws + o_Ure2);
  u16* Ure3 = (u16*)(ws + o_Ure3);
  u16* W2p  = (u16*)(ws + o_W2p);
  u16* W3p  = (u16*)(ws + o_W3p);
  u16* W1p  = (u16*)(ws + o_W1p);
  u16* xpad = (u16*)(ws + o_xpad);
  u32* x1p  = (u32*)(ws + o_x1);
  u32* xsp  = (u32*)(ws + o_xs);

  hipMemsetAsync(ws + o_h, 0, SZ_H + 4096, stream);   // tags -> 0 (invalid), counters -> 0

  prep_sv<<<dim3(2), dim3(256), 0, stream>>>(g1, be1, m1, v1, (float*)(ws+o_s), (float*)(ws+o_tv));
  transpose_pack<<<dim3(8,32), dim3(256), 0, stream>>>(U1, nullptr, Ure1);
  transpose_pack<<<dim3(8,32), dim3(256), 0, stream>>>(U2, nullptr, Ure2);
  transpose_pack<<<dim3(8,32), dim3(256), 0, stream>>>(U3, nullptr, Ure3);
  transpose_pack<<<dim3(8,32), dim3(256), 0, stream>>>(W3, nullptr, W3p);
  transpose_pack<<<dim3(8,32), dim3(256), 0, stream>>>(W2, (const float*)(ws+o_s), W2p);
  prep_b2p<<<dim3(8), dim3(256), 0, stream>>>(W2, b2, (const float*)(ws+o_tv), (float*)(ws+o_b2p));
  pack_w1<<<dim3(8), dim3(256), 0, stream>>>(W1, W1p);
  pack_x<<<dim3(4096), dim3(256), 0, stream>>>(x, xpad);

  scan_all<<<dim3(192), dim3(256), 0, stream>>>(
      Ure1, Ure2, Ure3, W1p, W2p, W3p, xpad,
      b1, (const float*)(ws+o_b2p), b3,
      (u32*)(ws+o_h), x1p, xsp,
      (float*)(ws+o_h3), (u32*)(ws+o_cnt));

  head_k<<<dim3(64), dim3(256), 0, stream>>>((const float*)(ws+o_h3),
      d1w, d1b, g2, be2, m2, v2, d2w, d2b, hw, hb, d4w, d4b, d5w, d5b, rw, rb,
      (float*)d_out);
}